// Round 11
// baseline (89.864 us; speedup 1.0000x reference)
//
#include <hip/hip_runtime.h>
#include <math.h>

#define THREADS 256
#define TMAXB 128  // k_tmax blocks -> TMAXB*4 wave partials

// ws layout (bytes), all regions disjoint:
//   0:    uint   c1          (finalize ticket, init 0 by k_tmax blk0)
//   64:   float  bmax        (by k_tmax blk0; cross-dispatch -> plain load safe)
//   1024: float  pmax[512]   (per-wave tmax partials, plain stores)      [1024,3072)
//   4096: double psumd[8]    (64B-strided accumulators, init 0)          [4096,4608)
//   8192: uint   binmin[nb]  (ordered-key minima, init 0xFFFFFFFF)       [8192,9216)

__device__ __forceinline__ float wmaxAll(float v) {
  #pragma unroll
  for (int o = 32; o > 0; o >>= 1) v = fmaxf(v, __shfl_xor(v, o, 64));
  return v;
}
__device__ __forceinline__ float wsumAll(float v) {
  #pragma unroll
  for (int o = 32; o > 0; o >>= 1) v += __shfl_xor(v, o, 64);
  return v;
}
__device__ __forceinline__ double wsumAllD(double v) {
  #pragma unroll
  for (int o = 32; o > 0; o >>= 1) v += __shfl_xor(v, o, 64);
  return v;
}

// totally-ordered uint key for float (handles negatives)
__device__ __forceinline__ unsigned keyEnc(float f) {
  unsigned u = __float_as_uint(f);
  return (u & 0x80000000u) ? ~u : (u | 0x80000000u);
}
__device__ __forceinline__ float keyDec(unsigned k) {
  unsigned u = (k & 0x80000000u) ? (k ^ 0x80000000u) : ~k;
  return __uint_as_float(u);
}

__global__ __launch_bounds__(THREADS) void k_tmax(const float4* __restrict__ t4, int n4,
                                                  const float* __restrict__ t, int n,
                                                  const float* __restrict__ bins, int nb,
                                                  float* __restrict__ pmax,
                                                  float* __restrict__ bmax,
                                                  unsigned* __restrict__ c1,
                                                  double* __restrict__ psumd,
                                                  unsigned* __restrict__ binmin) {
  const int tid = threadIdx.x;
  const int lane = tid & 63, w = tid >> 6;
  float v = 0.0f;  // target > 0
  int idx = blockIdx.x * THREADS + tid;
  int stride = gridDim.x * THREADS;
  for (int i = idx; i < n4; i += stride) {
    float4 a = t4[i];
    v = fmaxf(v, fmaxf(fmaxf(a.x, a.y), fmaxf(a.z, a.w)));
  }
  for (int i = n4 * 4 + idx; i < n; i += stride) v = fmaxf(v, t[i]);
  v = wmaxAll(v);
  if (lane == 0) pmax[blockIdx.x * 4 + w] = v;

  if (blockIdx.x == 0) {
    for (int i = tid; i < nb; i += THREADS) binmin[i] = 0xFFFFFFFFu;
    if (tid < 8) psumd[tid * 8] = 0.0;
    if (tid == 0) *c1 = 0u;
    if (w == 0) {
      float bv = 0.0f;
      for (int i = lane; i < nb; i += 64) bv = fmaxf(bv, bins[i]);
      bv = wmaxAll(bv);
      if (lane == 0) *bmax = bv;
    }
  }
}

// One pass over pixels: each block stages its 1024 normalized pixels in LDS.
//   phase A: per-thread (4 pixels) min over bins  -> term2 partial sum
//   phase B: per-thread (bin tid) min over block's pixels -> atomicMin binmin
// Last-arriving block (ticket) finalizes.
__global__ __launch_bounds__(THREADS) void k_comb(const float4* __restrict__ t4, int n4,
                                                  const float* __restrict__ t, int n,
                                                  const float* __restrict__ bins, int nb,
                                                  const float* __restrict__ pmax,
                                                  const float* __restrict__ bmaxp,
                                                  double* __restrict__ psumd,
                                                  unsigned* __restrict__ binmin,
                                                  unsigned* __restrict__ c1,
                                                  float* __restrict__ out, int G) {
  __shared__ float sb[256], hb[256];  // b^2, -2b
  __shared__ float tp[1024];          // this block's normalized pixels
  __shared__ float ss[4];
  __shared__ double ds[4];
  __shared__ unsigned sticket;

  const int tid = threadIdx.x;
  const int lane = tid & 63, w = tid >> 6;
  const int bid = blockIdx.x;
  const int ntail = n - n4 * 4;

  // scales (both cross-dispatch: plain loads safe)
  float v = 0.0f;
  for (int i = lane; i < TMAXB * 4; i += 64) v = fmaxf(v, pmax[i]);
  const float itf = 1.0f / wmaxAll(v);
  const float ibf = 1.0f / *bmaxp;

  for (int i = tid; i < nb && i < 256; i += THREADS) {
    float b = bins[i] * ibf;
    sb[i] = b * b;
    hb[i] = -(b + b);
  }

  const int idx = bid * THREADS + tid;
  const bool has = (idx < n4);
  float t0 = 0.f, t1 = 0.f, t2 = 0.f, t3 = 0.f;
  if (has) {
    float4 a = t4[idx];
    t0 = a.x * itf; t1 = a.y * itf; t2 = a.z * itf; t3 = a.w * itf;
    *(float4*)&tp[tid * 4] = make_float4(t0, t1, t2, t3);
  }
  __syncthreads();

  // ---- phase A: pixel-min over bins (term2) ----
  float lsum = 0.0f;
  if (has) {
    float m0 = 1e30f, m1 = 1e30f, m2 = 1e30f, m3 = 1e30f;
    #pragma unroll 8
    for (int j = 0; j < nb; j++) {
      float s = sb[j], h = hb[j];
      m0 = fminf(m0, fmaf(h, t0, s));
      m1 = fminf(m1, fmaf(h, t1, s));
      m2 = fminf(m2, fmaf(h, t2, s));
      m3 = fminf(m3, fmaf(h, t3, s));
    }
    lsum = (fmaf(t0, t0, m0) + fmaf(t1, t1, m1)) + (fmaf(t2, t2, m2) + fmaf(t3, t3, m3));
  }
  if (bid == 0 && tid < ntail) {
    float tv = t[n4 * 4 + tid] * itf;
    float m = 1e30f;
    for (int j = 0; j < nb; j++) m = fminf(m, fmaf(hb[j], tv, sb[j]));
    lsum += fmaf(tv, tv, m);
  }

  // ---- phase B: bin-min over this block's pixels (term1) ----
  // thread tid owns bin tid; value keyed as (t-b)^2 - b^2 (b^2 re-added in finalize)
  const int nf4 = n4 - bid * THREADS;
  const int P = 4 * (nf4 < THREADS ? (nf4 > 0 ? nf4 : 0) : THREADS);
  float bnv = 0.f, mb2 = 0.f;
  if (tid < nb) { bnv = bins[tid] * ibf; mb2 = -bnv * bnv; }
  float ma = 1e30f, mb = 1e30f, mc = 1e30f, md = 1e30f;
  for (int p = 0; p < P; p += 4) {
    float4 q = *(const float4*)&tp[p];  // uniform addr -> LDS broadcast
    float u0 = q.x - bnv, u1 = q.y - bnv, u2 = q.z - bnv, u3 = q.w - bnv;
    ma = fminf(ma, fmaf(u0, u0, mb2));
    mb = fminf(mb, fmaf(u1, u1, mb2));
    mc = fminf(mc, fmaf(u2, u2, mb2));
    md = fminf(md, fmaf(u3, u3, mb2));
  }
  if (bid == 0) {
    for (int i = 0; i < ntail; i++) {
      float tv = t[n4 * 4 + i] * itf;
      float u = tv - bnv;
      ma = fminf(ma, fmaf(u, u, mb2));
    }
  }
  if (tid < nb) {
    float bm = fminf(fminf(ma, mb), fminf(mc, md));
    atomicMin(&binmin[tid], keyEnc(bm));
  }

  // term2 partial -> strided double accumulator
  float s = wsumAll(lsum);
  if (lane == 0) ss[w] = s;
  __syncthreads();
  if (tid == 0)
    atomicAdd(&psumd[(bid & 7) * 8], (double)((ss[0] + ss[1]) + (ss[2] + ss[3])));

  // ---- last-block finalize (ticket; atomics-only cross-block state) ----
  asm volatile("s_waitcnt vmcnt(0)" ::: "memory");  // our atomics acked
  if (tid == 0) sticket = atomicAdd(c1, 1u);
  __syncthreads();
  if (sticket == (unsigned)(G - 1)) {
    double tsum = 0.0;
    for (int b = tid; b < nb; b += THREADS) {
      unsigned key = __hip_atomic_load(&binmin[b], __ATOMIC_RELAXED,
                                       __HIP_MEMORY_SCOPE_AGENT);
      float m = keyDec(key);
      float bv = bins[b] * ibf;
      float val = fmaf(bv, bv, m);              // add back b^2
      tsum += (m < 1e29f) ? (double)val : 0.0;  // all-inf row -> 0 per reference
    }
    if (tid < 8)
      tsum += __hip_atomic_load(&psumd[tid * 8], __ATOMIC_RELAXED,
                                __HIP_MEMORY_SCOPE_AGENT);
    tsum = wsumAllD(tsum);
    if (lane == 0) ds[w] = tsum;
    __syncthreads();
    if (tid == 0) out[0] = (float)((ds[0] + ds[1]) + (ds[2] + ds[3]));
  }
}

extern "C" void kernel_launch(void* const* d_in, const int* in_sizes, int n_in,
                              void* d_out, int out_size, void* d_ws, size_t ws_size,
                              hipStream_t stream) {
  const float* target = (const float*)d_in[0];
  const float* bins = (const float*)d_in[1];
  const int n = in_sizes[0];   // 307200
  const int nb = in_sizes[1];  // 256
  float* out = (float*)d_out;

  unsigned* c1 = (unsigned*)d_ws;                     // [0,4)
  float* bmax = (float*)((char*)d_ws + 64);           // [64,68)
  float* pmax = (float*)((char*)d_ws + 1024);         // [1024,3072)
  double* psumd = (double*)((char*)d_ws + 4096);      // [4096,4608)
  unsigned* binmin = (unsigned*)((char*)d_ws + 8192); // [8192,9216)

  const int n4 = n / 4;
  const float4* t4 = (const float4*)target;

  k_tmax<<<TMAXB, THREADS, 0, stream>>>(t4, n4, target, n, bins, nb,
                                        pmax, bmax, c1, psumd, binmin);

  const int G = (n4 + THREADS - 1) / THREADS;  // 300 blocks, one float4/thread
  k_comb<<<G, THREADS, 0, stream>>>(t4, n4, target, n, bins, nb, pmax, bmax,
                                    psumd, binmin, c1, out, G);
}